// Round 3
// baseline (215.698 us; speedup 1.0000x reference)
//
#include <hip/hip_runtime.h>
#include <hip/hip_bf16.h>

#define B_DIM 8
#define C_DIM 256
#define S_DIM 2304

// srcT/dstT layout: MFMA-fragment-tiled  [B][S/16][C/8][16 rows][8 k]
//   T(s,c) = (s>>4)*4096 + (c>>3)*128 + (s&15)*8 + (c&7)      (elems)
// A wave's A/B fragment load for mfma_16x16x32_bf16 becomes base + lane*16B
// -> one fully coalesced 1 KB global_load_dwordx4 from the XCD-resident L2.

typedef __attribute__((ext_vector_type(8))) short short8;
typedef __attribute__((ext_vector_type(4))) float floatx4;

// ---------------------------------------------------------------------------
// Kernel 1: per-(b,s) L2-normalize over C, f32 [B,C,S] -> bf16 tiled layout.
// This round: 512 threads/block (was 256) -> ~18 waves/CU so the ~900-cyc HBM
// read latency is covered (Little's law: need ~9 KB in flight/CU; 18 waves x
// 8x256B unrolled loads = 36 KB). Same verified tiled-write mapping.
// ---------------------------------------------------------------------------
__global__ __launch_bounds__(512) void norm_transpose_kernel(
    const float* __restrict__ src, const float* __restrict__ dst,
    __hip_bfloat16* __restrict__ srcT, __hip_bfloat16* __restrict__ dstT) {
    const int s0 = blockIdx.x * 64;
    const int b  = blockIdx.y;
    const float* in = (blockIdx.z == 0 ? src : dst) + (size_t)b * C_DIM * S_DIM;
    __hip_bfloat16* out = (blockIdx.z == 0 ? srcT : dstT) + (size_t)b * S_DIM * C_DIM;

    __shared__ __align__(16) __hip_bfloat16 tile[64][C_DIM + 8];
    __shared__ float red[8][64];
    __shared__ float invn[64];

    const int t  = threadIdx.x;
    const int l  = t & 63;
    const int wv = t >> 6;          // 0..7

    float ss = 0.f;
#pragma unroll 8
    for (int c = wv; c < C_DIM; c += 8) {
        float v = in[(size_t)c * S_DIM + s0 + l];
        ss += v * v;
        tile[l][c] = __float2bfloat16(v);
    }
    red[wv][l] = ss;
    __syncthreads();
    if (t < 64) {
        float a = 0.f;
#pragma unroll
        for (int w = 0; w < 8; ++w) a += red[w][t];
        invn[t] = rsqrtf(a);
    }
    __syncthreads();

    // Emit tiled layout: 64x256 elems = 16384; 512 thr x short8 -> 4 iters.
    // iter 'it' writes 16-row group 'it'; per-wave LDS reads are 2 lanes/bank
    // (free) and 16 B stores per 16-lane group are contiguous (1 KB/wave).
#pragma unroll
    for (int it = 0; it < 4; ++it) {
        int gidx = it * 512 + t;
        int fm   = gidx & 15;          // row within 16-group
        int cg   = (gidx >> 4) & 31;   // k-chunk (8 bf16)
        int sg   = it;                 // row-group within block (0..3)
        int srow = sg * 16 + fm;
        float inv = invn[srow];
        union { short8 v; __hip_bfloat16 h[8]; } u, o;
        u.v = *(const short8*)&tile[srow][cg * 8];
#pragma unroll
        for (int j = 0; j < 8; ++j)
            o.h[j] = __float2bfloat16(__bfloat162float(u.h[j]) * inv);
        *(short8*)&out[(size_t)((s0 >> 4) + sg) * 4096 + cg * 128 + fm * 8] = o.v;
    }
}

// ---------------------------------------------------------------------------
// Kernel 2: per-batch GEMM  out[b][m][n] = relu( sum_k A[m][k]*B[n][k] )
// Zero-LDS, zero-barrier: fragments stream from the XCD-resident L2 via
// coalesced 1 KB loads (reg ping-pong, depth 1 ~ 240 issue-cycles lead at
// 3 waves/SIMD vs ~200 cyc L2 latency). This round the epilogue LDS
// transpose round-trip (64 KB LDS traffic + 4 __syncthreads per block) is
// replaced by DIRECT stores: per (i,j,r) each 16-lane group writes 16
// consecutive f32 = one aligned 64 B line (C/D map col=lane&15,
// row=(lane>>4)*4+r, m89-verified). Nontemporal so the 21 MB/batch C stream
// doesn't evict the 2.36 MB A/B panels from L2.
// ---------------------------------------------------------------------------
__global__ __launch_bounds__(256, 3) void gemm_relu_kernel(
    const __hip_bfloat16* __restrict__ At, const __hip_bfloat16* __restrict__ Bt,
    float* __restrict__ out) {
    const int id = blockIdx.x;
    const int b  = id & 7;          // batch -> XCD (id%8 round-robin)
    const int q  = id >> 3;
    const int m0 = (q % 18) * 128;
    const int n0 = (q / 18) * 128;

    const int t    = threadIdx.x;
    const int lane = t & 63;
    const int wv   = t >> 6;

    const int fm = lane & 15;
    const int wr = (wv >> 1) << 6;
    const int wc = (wv & 1) << 6;
    const int rq = (lane >> 4) << 2;

    // Per-lane fragment base: tiled layout makes this base + lane*16B.
    const __hip_bfloat16* pA = At + (size_t)b * S_DIM * C_DIM
                             + (size_t)((m0 + wr) >> 4) * 4096 + lane * 8;
    const __hip_bfloat16* pB = Bt + (size_t)b * S_DIM * C_DIM
                             + (size_t)((n0 + wc) >> 4) * 4096 + lane * 8;
    // frag i: +i*4096 (next 16-row group); k-iter ki: +ki*512 (4 k-chunks)

    floatx4 acc[4][4] = {};
    short8 a0[4], b0[4], a1[4], b1[4];

#pragma unroll
    for (int i = 0; i < 4; ++i) {
        a0[i] = *(const short8*)(pA + i * 4096);
        b0[i] = *(const short8*)(pB + i * 4096);
    }

#pragma unroll
    for (int ki = 0; ki < 8; ki += 2) {
        // prefetch iter ki+1 while computing iter ki
#pragma unroll
        for (int i = 0; i < 4; ++i) {
            a1[i] = *(const short8*)(pA + i * 4096 + (ki + 1) * 512);
            b1[i] = *(const short8*)(pB + i * 4096 + (ki + 1) * 512);
        }
        __builtin_amdgcn_s_setprio(1);
#pragma unroll
        for (int i = 0; i < 4; ++i)
#pragma unroll
            for (int j = 0; j < 4; ++j)
                acc[i][j] = __builtin_amdgcn_mfma_f32_16x16x32_bf16(a0[i], b0[j], acc[i][j], 0, 0, 0);
        __builtin_amdgcn_s_setprio(0);

        if (ki + 2 < 8) {
#pragma unroll
            for (int i = 0; i < 4; ++i) {
                a0[i] = *(const short8*)(pA + i * 4096 + (ki + 2) * 512);
                b0[i] = *(const short8*)(pB + i * 4096 + (ki + 2) * 512);
            }
        }
        __builtin_amdgcn_s_setprio(1);
#pragma unroll
        for (int i = 0; i < 4; ++i)
#pragma unroll
            for (int j = 0; j < 4; ++j)
                acc[i][j] = __builtin_amdgcn_mfma_f32_16x16x32_bf16(a1[i], b1[j], acc[i][j], 0, 0, 0);
        __builtin_amdgcn_s_setprio(0);
    }

    // Epilogue: direct nontemporal stores, ReLU fused. Row for acc[i][*][r]
    // is m0+wr+i*16+rq+r; col for acc[*][j][*] is n0+wc+j*16+fm. Each
    // (i,j,r) is a 64 B-aligned 16-f32 line per 16-lane group; the j-loop
    // walks 4 adjacent lines (256 B contiguous per row).
    float* Cp = out + (size_t)b * S_DIM * S_DIM + n0 + wc + fm;
#pragma unroll
    for (int i = 0; i < 4; ++i) {
#pragma unroll
        for (int r = 0; r < 4; ++r) {
            float* rowp = Cp + (size_t)(m0 + wr + i * 16 + rq + r) * S_DIM;
#pragma unroll
            for (int j = 0; j < 4; ++j)
                __builtin_nontemporal_store(fmaxf(acc[i][j][r], 0.f), rowp + j * 16);
        }
    }
}

extern "C" void kernel_launch(void* const* d_in, const int* in_sizes, int n_in,
                              void* d_out, int out_size, void* d_ws, size_t ws_size,
                              hipStream_t stream) {
    const float* src = (const float*)d_in[0];
    const float* dst = (const float*)d_in[1];
    float* out = (float*)d_out;

    __hip_bfloat16* srcT = (__hip_bfloat16*)d_ws;
    __hip_bfloat16* dstT = srcT + (size_t)B_DIM * S_DIM * C_DIM;

    dim3 g1(S_DIM / 64, B_DIM, 2);
    norm_transpose_kernel<<<g1, 512, 0, stream>>>(src, dst, srcT, dstT);

    gemm_relu_kernel<<<dim3(B_DIM * 18 * 18), 256, 0, stream>>>(srcT, dstT, out);
}

// Round 5
// 209.150 us; speedup vs baseline: 1.0313x; 1.0313x over previous
//
#include <hip/hip_runtime.h>
#include <hip/hip_bf16.h>

#define B_DIM 8
#define C_DIM 256
#define S_DIM 2304

// srcT/dstT layout: MFMA-fragment-tiled  [B][S/16][C/8][16 rows][8 k]
//   T(s,c) = (s>>4)*4096 + (c>>3)*128 + (s&15)*8 + (c&7)      (elems)
// A wave's A/B fragment load for mfma_16x16x32_bf16 becomes base + lane*16B
// -> one fully coalesced 1 KB global_load_dwordx4 from the XCD-resident L2.

typedef __attribute__((ext_vector_type(8))) short short8;
typedef __attribute__((ext_vector_type(4))) float floatx4;

// ---------------------------------------------------------------------------
// Kernel 1: per-(b,s) L2-normalize over C, f32 [B,C,S] -> bf16 tiled layout.
// Exact verified R1/R2 version (256 threads).  Model: ~8-10 us, BW-bound.
// ---------------------------------------------------------------------------
__global__ __launch_bounds__(256) void norm_transpose_kernel(
    const float* __restrict__ src, const float* __restrict__ dst,
    __hip_bfloat16* __restrict__ srcT, __hip_bfloat16* __restrict__ dstT) {
    const int s0 = blockIdx.x * 64;
    const int b  = blockIdx.y;
    const float* in = (blockIdx.z == 0 ? src : dst) + (size_t)b * C_DIM * S_DIM;
    __hip_bfloat16* out = (blockIdx.z == 0 ? srcT : dstT) + (size_t)b * S_DIM * C_DIM;

    __shared__ __align__(16) __hip_bfloat16 tile[64][C_DIM + 8];
    __shared__ float red[4][64];
    __shared__ float invn[64];

    const int t  = threadIdx.x;
    const int l  = t & 63;
    const int wv = t >> 6;

    float ss = 0.f;
#pragma unroll 8
    for (int c = wv; c < C_DIM; c += 4) {
        float v = in[(size_t)c * S_DIM + s0 + l];
        ss += v * v;
        tile[l][c] = __float2bfloat16(v);
    }
    red[wv][l] = ss;
    __syncthreads();
    if (t < 64) invn[t] = rsqrtf(red[0][t] + red[1][t] + red[2][t] + red[3][t]);
    __syncthreads();

    // Emit tiled layout. Per 16-lane group the 16 B stores are contiguous
    // (stride 8 elems in fm) -> 1 KB contiguous per wave.
#pragma unroll
    for (int it = 0; it < 8; ++it) {
        int gidx = it * 256 + t;
        int fm   = gidx & 15;          // row within 16-group
        int cg   = (gidx >> 4) & 31;   // k-chunk (8 bf16)
        int sg   = gidx >> 9;          // row-group within block (0..3)
        int srow = sg * 16 + fm;
        float inv = invn[srow];
        union { short8 v; __hip_bfloat16 h[8]; } u, o;
        u.v = *(const short8*)&tile[srow][cg * 8];
#pragma unroll
        for (int j = 0; j < 8; ++j)
            o.h[j] = __float2bfloat16(__bfloat162float(u.h[j]) * inv);
        *(short8*)&out[(size_t)((s0 >> 4) + sg) * 4096 + cg * 128 + fm * 8] = o.v;
    }
}

// ---------------------------------------------------------------------------
// Kernel 2: per-batch GEMM  out[b][m][n] = relu( sum_k A[m][k]*B[n][k] )
// Zero-LDS, zero-barrier main loop: fragments stream from the XCD-resident
// L2 via coalesced 1 KB loads, register ping-pong double buffer.
// Epilogue = verified R1 LDS-transpose path, final stores NONTEMPORAL
// vector-float4 (ext_vector_type -- the HIP float4 class is rejected by
// __builtin_nontemporal_store):
//   - floatx4 x 64 lanes = 1 KB dense per instruction, full 128-B lines
//     (R3's scalar NT stores caused partial-sector DRAM RMW -> +5 us).
//   - NT bypasses L2, so the 21 MB/batch C stream no longer evicts the
//     2.36 MB A/B panels from the XCD L2 -> fragment loads stay L2-fed
//     and overlap with the store drain instead of stalling on L3.
// ---------------------------------------------------------------------------
__global__ __launch_bounds__(256, 3) void gemm_relu_kernel(
    const __hip_bfloat16* __restrict__ At, const __hip_bfloat16* __restrict__ Bt,
    float* __restrict__ out) {
    const int id = blockIdx.x;
    const int b  = id & 7;          // batch -> XCD (id%8 round-robin)
    const int q  = id >> 3;
    const int m0 = (q % 18) * 128;
    const int n0 = (q / 18) * 128;

    __shared__ __align__(16) float Cs[64 * 132];

    const int t    = threadIdx.x;
    const int lane = t & 63;
    const int wv   = t >> 6;

    const int fm = lane & 15;
    const int wr = (wv >> 1) << 6;
    const int wc = (wv & 1) << 6;
    const int rq = (lane >> 4) << 2;

    // Per-lane fragment base: tiled layout makes this base + lane*16B.
    const __hip_bfloat16* pA = At + (size_t)b * S_DIM * C_DIM
                             + (size_t)((m0 + wr) >> 4) * 4096 + lane * 8;
    const __hip_bfloat16* pB = Bt + (size_t)b * S_DIM * C_DIM
                             + (size_t)((n0 + wc) >> 4) * 4096 + lane * 8;
    // frag i: +i*4096 (next 16-row group); k-iter ki: +ki*512 (4 k-chunks)

    floatx4 acc[4][4] = {};
    short8 a0[4], b0[4], a1[4], b1[4];

#pragma unroll
    for (int i = 0; i < 4; ++i) {
        a0[i] = *(const short8*)(pA + i * 4096);
        b0[i] = *(const short8*)(pB + i * 4096);
    }

#pragma unroll
    for (int ki = 0; ki < 8; ki += 2) {
        // prefetch iter ki+1 while computing iter ki
#pragma unroll
        for (int i = 0; i < 4; ++i) {
            a1[i] = *(const short8*)(pA + i * 4096 + (ki + 1) * 512);
            b1[i] = *(const short8*)(pB + i * 4096 + (ki + 1) * 512);
        }
        __builtin_amdgcn_s_setprio(1);
#pragma unroll
        for (int i = 0; i < 4; ++i)
#pragma unroll
            for (int j = 0; j < 4; ++j)
                acc[i][j] = __builtin_amdgcn_mfma_f32_16x16x32_bf16(a0[i], b0[j], acc[i][j], 0, 0, 0);
        __builtin_amdgcn_s_setprio(0);

        if (ki + 2 < 8) {
#pragma unroll
            for (int i = 0; i < 4; ++i) {
                a0[i] = *(const short8*)(pA + i * 4096 + (ki + 2) * 512);
                b0[i] = *(const short8*)(pB + i * 4096 + (ki + 2) * 512);
            }
        }
        __builtin_amdgcn_s_setprio(1);
#pragma unroll
        for (int i = 0; i < 4; ++i)
#pragma unroll
            for (int j = 0; j < 4; ++j)
                acc[i][j] = __builtin_amdgcn_mfma_f32_16x16x32_bf16(a1[i], b1[j], acc[i][j], 0, 0, 0);
        __builtin_amdgcn_s_setprio(0);
    }

    // Epilogue: acc -> padded LDS f32 tile -> dense nontemporal floatx4
    // stores (1 KB/wave-instr, full lines), ReLU fused.  Verified mapping.
    float* Cp = out + (size_t)b * S_DIM * S_DIM;
#pragma unroll
    for (int p = 0; p < 2; ++p) {
        __syncthreads();   // prior Cs reads done (and wave convergence)
#pragma unroll
        for (int i2 = 0; i2 < 2; ++i2) {
            int i = 2 * p + i2;
            int slot = (wr >> 1) + i2 * 16 + rq;
#pragma unroll
            for (int j = 0; j < 4; ++j) {
                int col = wc + j * 16 + fm;
#pragma unroll
                for (int r = 0; r < 4; ++r)
                    Cs[(slot + r) * 132 + col] = fmaxf(acc[i][j][r], 0.f);
            }
        }
        __syncthreads();
#pragma unroll
        for (int it = 0; it < 8; ++it) {
            int idx  = it * 256 + t;
            int srow = idx >> 5;
            int c4   = (idx & 31) << 2;
            floatx4 v = *(const floatx4*)&Cs[srow * 132 + c4];
            int lrow = 32 * p + (srow & 31) + ((srow >> 5) << 6);
            __builtin_nontemporal_store(
                v, (floatx4*)&Cp[(size_t)(m0 + lrow) * S_DIM + n0 + c4]);
        }
    }
}

extern "C" void kernel_launch(void* const* d_in, const int* in_sizes, int n_in,
                              void* d_out, int out_size, void* d_ws, size_t ws_size,
                              hipStream_t stream) {
    const float* src = (const float*)d_in[0];
    const float* dst = (const float*)d_in[1];
    float* out = (float*)d_out;

    __hip_bfloat16* srcT = (__hip_bfloat16*)d_ws;
    __hip_bfloat16* dstT = srcT + (size_t)B_DIM * S_DIM * C_DIM;

    dim3 g1(S_DIM / 64, B_DIM, 2);
    norm_transpose_kernel<<<g1, 256, 0, stream>>>(src, dst, srcT, dstT);

    gemm_relu_kernel<<<dim3(B_DIM * 18 * 18), 256, 0, stream>>>(srcT, dstT, out);
}

// Round 6
// 207.175 us; speedup vs baseline: 1.0411x; 1.0095x over previous
//
#include <hip/hip_runtime.h>
#include <hip/hip_bf16.h>

#define B_DIM 8
#define C_DIM 256
#define S_DIM 2304

// srcT/dstT layout: MFMA-fragment-tiled  [B][S/16][C/8][16 rows][8 k]
//   T(s,c) = (s>>4)*4096 + (c>>3)*128 + (s&15)*8 + (c&7)      (elems)
// A wave's A/B fragment load for mfma_16x16x32_bf16 becomes base + lane*16B
// -> one fully coalesced 1 KB global_load_dwordx4 from the XCD-resident L2.

typedef __attribute__((ext_vector_type(8))) short short8;
typedef __attribute__((ext_vector_type(4))) float floatx4;

// ---------------------------------------------------------------------------
// Kernel 1: per-(b,s) L2-normalize over C, f32 [B,C,S] -> bf16 tiled layout.
// THIS ROUND: LDS staging rebuilt around b128 writes + XOR swizzle.
//   old: per-element b16 writes, banks 4*(l&7) -> true 8-way serialization
//        on every staged write (~3-4 us aggregate).
//   new: each thread packs 8 c-values (one octet) -> ONE ds_write_b128 at
//        byteInRow = 16*(oct ^ (l&7)); row stride 512 B == 0 mod 32 banks.
//        8 lanes/4-bank-group x 16 B = exactly the 128 B/clk LDS wire rate
//        (full bandwidth, zero conflict overhead); readout uses the same
//        involution 16*(cg ^ (srow&7)) -> also full-BW. LDS 33.8 -> 32 KB.
// ---------------------------------------------------------------------------
__global__ __launch_bounds__(256) void norm_transpose_kernel(
    const float* __restrict__ src, const float* __restrict__ dst,
    __hip_bfloat16* __restrict__ srcT, __hip_bfloat16* __restrict__ dstT) {
    const int s0 = blockIdx.x * 64;
    const int b  = blockIdx.y;
    const float* in = (blockIdx.z == 0 ? src : dst) + (size_t)b * C_DIM * S_DIM;
    __hip_bfloat16* out = (blockIdx.z == 0 ? srcT : dstT) + (size_t)b * S_DIM * C_DIM;

    __shared__ __align__(16) __hip_bfloat16 tile[64][C_DIM];   // 32 KB, swizzled
    __shared__ float red[4][64];
    __shared__ float invn[64];

    const int t  = threadIdx.x;
    const int l  = t & 63;
    const int wv = t >> 6;

    // Thread (wv,l) owns s = s0+l and c-octets oct = 4q+wv, q in [0,8).
    // Loads: in[c*S + s0 + l] -> 64-lane contiguous 256 B (same coalescing
    // as before, c-order per wave merely permuted; block coverage identical).
    float ss = 0.f;
#pragma unroll 2
    for (int q = 0; q < 8; ++q) {
        int oct = 4 * q + wv;
        union { short8 v; __hip_bfloat16 h[8]; } o;
#pragma unroll
        for (int j = 0; j < 8; ++j) {
            float v = in[(size_t)(oct * 8 + j) * S_DIM + s0 + l];
            ss += v * v;
            o.h[j] = __float2bfloat16(v);
        }
        *(short8*)((char*)&tile[l][0] + ((oct * 16) ^ ((l & 7) << 4))) = o.v;
    }
    red[wv][l] = ss;
    __syncthreads();
    if (t < 64) invn[t] = rsqrtf(red[0][t] + red[1][t] + red[2][t] + red[3][t]);
    __syncthreads();

    // Emit tiled layout. Per 16-lane group the 16 B stores are contiguous
    // (stride 8 elems in fm) -> 1 KB contiguous per wave.
#pragma unroll
    for (int it = 0; it < 8; ++it) {
        int gidx = it * 256 + t;
        int fm   = gidx & 15;          // row within 16-group
        int cg   = (gidx >> 4) & 31;   // k-chunk (8 bf16) == octet index
        int sg   = gidx >> 9;          // row-group within block (0..3)
        int srow = sg * 16 + fm;
        float inv = invn[srow];
        union { short8 v; __hip_bfloat16 h[8]; } u, o;
        u.v = *(const short8*)((const char*)&tile[srow][0]
                               + ((cg * 16) ^ ((srow & 7) << 4)));
#pragma unroll
        for (int j = 0; j < 8; ++j)
            o.h[j] = __float2bfloat16(__bfloat162float(u.h[j]) * inv);
        *(short8*)&out[(size_t)((s0 >> 4) + sg) * 4096 + cg * 128 + fm * 8] = o.v;
    }
}

// ---------------------------------------------------------------------------
// Kernel 2: per-batch GEMM  out[b][m][n] = relu( sum_k A[m][k]*B[n][k] )
// EXACT R5 best-verified version (209.15 us total). Zero-LDS, zero-barrier
// main loop: fragments stream from the XCD-resident L2 via coalesced 1 KB
// loads, register ping-pong double buffer. Epilogue: LDS transpose + dense
// nontemporal floatx4 stores (1 KB/wave-instr, full 128-B lines; NT keeps
// the 21 MB/batch C stream from evicting the 2.36 MB A/B panels from L2).
// ---------------------------------------------------------------------------
__global__ __launch_bounds__(256, 3) void gemm_relu_kernel(
    const __hip_bfloat16* __restrict__ At, const __hip_bfloat16* __restrict__ Bt,
    float* __restrict__ out) {
    const int id = blockIdx.x;
    const int b  = id & 7;          // batch -> XCD (id%8 round-robin)
    const int q  = id >> 3;
    const int m0 = (q % 18) * 128;
    const int n0 = (q / 18) * 128;

    __shared__ __align__(16) float Cs[64 * 132];

    const int t    = threadIdx.x;
    const int lane = t & 63;
    const int wv   = t >> 6;

    const int fm = lane & 15;
    const int wr = (wv >> 1) << 6;
    const int wc = (wv & 1) << 6;
    const int rq = (lane >> 4) << 2;

    // Per-lane fragment base: tiled layout makes this base + lane*16B.
    const __hip_bfloat16* pA = At + (size_t)b * S_DIM * C_DIM
                             + (size_t)((m0 + wr) >> 4) * 4096 + lane * 8;
    const __hip_bfloat16* pB = Bt + (size_t)b * S_DIM * C_DIM
                             + (size_t)((n0 + wc) >> 4) * 4096 + lane * 8;
    // frag i: +i*4096 (next 16-row group); k-iter ki: +ki*512 (4 k-chunks)

    floatx4 acc[4][4] = {};
    short8 a0[4], b0[4], a1[4], b1[4];

#pragma unroll
    for (int i = 0; i < 4; ++i) {
        a0[i] = *(const short8*)(pA + i * 4096);
        b0[i] = *(const short8*)(pB + i * 4096);
    }

#pragma unroll
    for (int ki = 0; ki < 8; ki += 2) {
        // prefetch iter ki+1 while computing iter ki
#pragma unroll
        for (int i = 0; i < 4; ++i) {
            a1[i] = *(const short8*)(pA + i * 4096 + (ki + 1) * 512);
            b1[i] = *(const short8*)(pB + i * 4096 + (ki + 1) * 512);
        }
        __builtin_amdgcn_s_setprio(1);
#pragma unroll
        for (int i = 0; i < 4; ++i)
#pragma unroll
            for (int j = 0; j < 4; ++j)
                acc[i][j] = __builtin_amdgcn_mfma_f32_16x16x32_bf16(a0[i], b0[j], acc[i][j], 0, 0, 0);
        __builtin_amdgcn_s_setprio(0);

        if (ki + 2 < 8) {
#pragma unroll
            for (int i = 0; i < 4; ++i) {
                a0[i] = *(const short8*)(pA + i * 4096 + (ki + 2) * 512);
                b0[i] = *(const short8*)(pB + i * 4096 + (ki + 2) * 512);
            }
        }
        __builtin_amdgcn_s_setprio(1);
#pragma unroll
        for (int i = 0; i < 4; ++i)
#pragma unroll
            for (int j = 0; j < 4; ++j)
                acc[i][j] = __builtin_amdgcn_mfma_f32_16x16x32_bf16(a1[i], b1[j], acc[i][j], 0, 0, 0);
        __builtin_amdgcn_s_setprio(0);
    }

    // Epilogue: acc -> padded LDS f32 tile -> dense nontemporal floatx4
    // stores (1 KB/wave-instr, full lines), ReLU fused.  Verified mapping.
    float* Cp = out + (size_t)b * S_DIM * S_DIM;
#pragma unroll
    for (int p = 0; p < 2; ++p) {
        __syncthreads();   // prior Cs reads done (and wave convergence)
#pragma unroll
        for (int i2 = 0; i2 < 2; ++i2) {
            int i = 2 * p + i2;
            int slot = (wr >> 1) + i2 * 16 + rq;
#pragma unroll
            for (int j = 0; j < 4; ++j) {
                int col = wc + j * 16 + fm;
#pragma unroll
                for (int r = 0; r < 4; ++r)
                    Cs[(slot + r) * 132 + col] = fmaxf(acc[i][j][r], 0.f);
            }
        }
        __syncthreads();
#pragma unroll
        for (int it = 0; it < 8; ++it) {
            int idx  = it * 256 + t;
            int srow = idx >> 5;
            int c4   = (idx & 31) << 2;
            floatx4 v = *(const floatx4*)&Cs[srow * 132 + c4];
            int lrow = 32 * p + (srow & 31) + ((srow >> 5) << 6);
            __builtin_nontemporal_store(
                v, (floatx4*)&Cp[(size_t)(m0 + lrow) * S_DIM + n0 + c4]);
        }
    }
}

extern "C" void kernel_launch(void* const* d_in, const int* in_sizes, int n_in,
                              void* d_out, int out_size, void* d_ws, size_t ws_size,
                              hipStream_t stream) {
    const float* src = (const float*)d_in[0];
    const float* dst = (const float*)d_in[1];
    float* out = (float*)d_out;

    __hip_bfloat16* srcT = (__hip_bfloat16*)d_ws;
    __hip_bfloat16* dstT = srcT + (size_t)B_DIM * S_DIM * C_DIM;

    dim3 g1(S_DIM / 64, B_DIM, 2);
    norm_transpose_kernel<<<g1, 256, 0, stream>>>(src, dst, srcT, dstT);

    gemm_relu_kernel<<<dim3(B_DIM * 18 * 18), 256, 0, stream>>>(srcT, dstT, out);
}